// Round 6
// baseline (1300.610 us; speedup 1.0000x reference)
//
#include <hip/hip_runtime.h>

#define N_ACTIVE 200000
#define N_IN 64
#define N_OUT 64
#define K_FILT 27
#define R_PAIRS 100000
#define TOTP (K_FILT * R_PAIRS)          // 2,700,000
#define RB 96                            // output rows per block
#define NB ((N_ACTIVE + RB - 1) / RB)    // 2084
#define NBUCK (NB * K_FILT)              // 56,268
#define NSB ((NBUCK + 255) / 256)        // 220
#define ELDS 2048                        // staged entries per block (mean 1296)
#define MAXG 256                         // group descriptors per block (mean ~83)

#define CF_BLOCKS (N_ACTIVE * N_IN / 8 / 256)    // 6250 convert_feat blocks
#define CW_BLOCKS K_FILT                          // 27 convert_wt blocks
#define HI_BLOCKS ((TOTP + 255) / 256)            // 10547 hist blocks

typedef __bf16 bf16x8 __attribute__((ext_vector_type(8)));
typedef float f32x4 __attribute__((ext_vector_type(4)));

__global__ __launch_bounds__(256) void zero_ints(int* __restrict__ p, int n) {
    int i = blockIdx.x * 256 + threadIdx.x;
    if (i < n) p[i] = 0;
}

// ---------------------------------------------------------------------------
// fused prep: convert_feat | convert_wt | hist
// ---------------------------------------------------------------------------
__global__ __launch_bounds__(256) void prep_fused(
    const float* __restrict__ feat, __bf16* __restrict__ featb,
    const float* __restrict__ wsrc, __bf16* __restrict__ wt,
    const int* __restrict__ out_idx, int* __restrict__ cnt)
{
    int bb = blockIdx.x, t = threadIdx.x;
    if (bb < CF_BLOCKS) {
        int i = bb * 256 + t;
        const f32x4* src = reinterpret_cast<const f32x4*>(feat) + 2 * (size_t)i;
        f32x4 v0 = __builtin_nontemporal_load(src);
        f32x4 v1 = __builtin_nontemporal_load(src + 1);
        bf16x8 o;
        o[0] = (__bf16)v0[0]; o[1] = (__bf16)v0[1]; o[2] = (__bf16)v0[2]; o[3] = (__bf16)v0[3];
        o[4] = (__bf16)v1[0]; o[5] = (__bf16)v1[1]; o[6] = (__bf16)v1[2]; o[7] = (__bf16)v1[3];
        reinterpret_cast<bf16x8*>(featb)[i] = o;
    } else if (bb < CF_BLOCKS + CW_BLOCKS) {
        int kf = bb - CF_BLOCKS;
        const float* wk = wsrc + kf * 4096;
        __bf16* wo = wt + kf * 4096;
        int o = t >> 2, i0 = (t & 3) * 16;
        bf16x8 a, b;
        #pragma unroll
        for (int j = 0; j < 8; ++j) a[j] = (__bf16)wk[(i0 + j) * 64 + o];
        #pragma unroll
        for (int j = 0; j < 8; ++j) b[j] = (__bf16)wk[(i0 + 8 + j) * 64 + o];
        *reinterpret_cast<bf16x8*>(wo + o * 64 + i0) = a;
        *reinterpret_cast<bf16x8*>(wo + o * 64 + i0 + 8) = b;
    } else {
        int p = (bb - CF_BLOCKS - CW_BLOCKS) * 256 + t;
        if (p < TOTP) {
            unsigned k = (unsigned)p / (unsigned)R_PAIRS;
            int b = (out_idx[p] / RB) * K_FILT + (int)k;
            atomicAdd(&cnt[b], 1);
        }
    }
}

// ---- hierarchical exclusive scan over NBUCK counters ----
__global__ __launch_bounds__(256) void scan1(const int* __restrict__ cnt,
                                             int* __restrict__ off,
                                             int* __restrict__ bsum) {
    __shared__ int s[256];
    int t = threadIdx.x, i = blockIdx.x * 256 + t;
    int v = (i < NBUCK) ? cnt[i] : 0;
    s[t] = v;
    __syncthreads();
    #pragma unroll
    for (int d = 1; d < 256; d <<= 1) {
        int x = (t >= d) ? s[t - d] : 0;
        __syncthreads();
        s[t] += x;
        __syncthreads();
    }
    if (i < NBUCK) off[i] = s[t] - v;
    if (t == 255) bsum[blockIdx.x] = s[255];
}

__global__ __launch_bounds__(256) void scan2(int* __restrict__ bsum) {
    __shared__ int s[256];
    int t = threadIdx.x;
    int v = (t < NSB) ? bsum[t] : 0;
    s[t] = v;
    __syncthreads();
    #pragma unroll
    for (int d = 1; d < 256; d <<= 1) {
        int x = (t >= d) ? s[t - d] : 0;
        __syncthreads();
        s[t] += x;
        __syncthreads();
    }
    if (t < NSB) bsum[t] = s[t] - v;
}

__global__ __launch_bounds__(256) void scan3(int* __restrict__ off,
                                             const int* __restrict__ bsum,
                                             int* __restrict__ cursor) {
    int t = threadIdx.x, i = blockIdx.x * 256 + t;
    if (i < NBUCK) {
        int v = off[i] + bsum[blockIdx.x];
        off[i] = v;
        cursor[i] = v;            // absolute cursor: scatter skips off[] read
    }
    if (i == 0) off[NBUCK] = TOTP;
}

// ---------------------------------------------------------------------------
// scatter pair -> bucket list; entry packed as (in_row << 7) | out_local
// ---------------------------------------------------------------------------
__global__ __launch_bounds__(256) void scatter_pack(const int* __restrict__ in_idx,
                                                    const int* __restrict__ out_idx,
                                                    int* __restrict__ cursor,
                                                    int* __restrict__ entries) {
    int p = blockIdx.x * 256 + threadIdx.x;
    if (p >= TOTP) return;
    unsigned k = (unsigned)p / (unsigned)R_PAIRS;
    int orow = out_idx[p];
    int iv = __builtin_nontemporal_load(&in_idx[p]);
    int rg = orow / RB;
    int bkt = rg * K_FILT + (int)k;
    int pos = atomicAdd(&cursor[bkt], 1);   // absolute position
    entries[pos] = (iv << 7) | (orow - rg * RB);
}

// ---------------------------------------------------------------------------
// conv: block owns 96 out rows. Entries staged in LDS; t0 builds a flat
// group-descriptor list (kf<<18 | startJ<<5 | nvalid). Each wave takes a
// contiguous range and runs a 4-deep explicit pipeline: A-frags for groups
// g..g+3 in flight while computing group g. MFMA layouts as r3 (verified).
// ---------------------------------------------------------------------------
__global__ __launch_bounds__(256) void conv_mfma(
    const __bf16* __restrict__ featb,   // [N_ACTIVE][64] bf16
    const __bf16* __restrict__ wtb,     // [K][o][i] bf16 transposed
    const float* __restrict__ bias,
    const int* __restrict__ off,        // [NBUCK+1]
    const int* __restrict__ entries,    // [TOTP] packed
    float* __restrict__ out)            // [N_ACTIVE][64] fp32
{
    __shared__ float outT[RB][68];      // 26,112 B
    __shared__ int   eLds[ELDS];        //  8,192 B
    __shared__ int   sOff[K_FILT + 1];
    __shared__ int   descLds[MAXG];     //  1,024 B
    __shared__ int   gCount;

    const int b = blockIdx.x;
    const int t = threadIdx.x;
    const int w = t >> 6;
    const int lane = t & 63;
    const int lrow = lane & 15;
    const int lkB  = (lane >> 4) * 8;
    const int rg4  = (lane >> 4) * 4;
    const int bK = b * K_FILT;

    if (t < K_FILT + 1) sOff[t] = off[bK + t];

    {   // zero out tile
        f32x4 z = {0.f, 0.f, 0.f, 0.f};
        f32x4* o4 = reinterpret_cast<f32x4*>(&outT[0][0]);
        #pragma unroll
        for (int j = 0; j < 7; ++j) {
            int i = j * 256 + t;
            if (i < RB * 68 / 4) o4[i] = z;
        }
    }

    const int blockStart = off[bK];
    const int total = off[bK + K_FILT] - blockStart;
    const int stged = total < ELDS ? total : ELDS;
    for (int i = t; i < stged; i += 256)
        eLds[i] = __builtin_nontemporal_load(&entries[blockStart + i]);
    __syncthreads();

    if (t == 0) {   // build flat group descriptor list
        int ng = 0;
        int bs = sOff[0];
        for (int kf = 0; kf < K_FILT; ++kf) {
            int s = sOff[kf] - bs;
            int c = sOff[kf + 1] - sOff[kf];
            for (int j = 0; j < c && ng < MAXG; j += 16) {
                int nv = c - j; if (nv > 16) nv = 16;
                descLds[ng++] = (kf << 18) | ((s + j) << 5) | nv;
            }
        }
        gCount = ng;
    }
    __syncthreads();

    const int nG = gCount;
    const int per = (nG + 3) >> 2;
    const int g0 = w * per;
    const int g1 = (g0 + per < nG) ? g0 + per : nG;

#define LOADG(g, A0, A1) do {                                                  \
        int d_ = descLds[g];                                                   \
        int sj_ = (d_ >> 5) & 0x1FFF, nv_ = d_ & 31;                           \
        int idx_ = sj_ + (lrow < nv_ ? lrow : 0);                              \
        int e_ = (idx_ < stged) ? eLds[idx_] : entries[blockStart + idx_];     \
        const __bf16* ap_ = featb + (size_t)(e_ >> 7) * 64 + lkB;              \
        A0 = *reinterpret_cast<const bf16x8*>(ap_);                            \
        A1 = *reinterpret_cast<const bf16x8*>(ap_ + 32);                       \
    } while (0)

#define COMPG(g, A0, A1) do {                                                  \
        int d_ = descLds[g];                                                   \
        int kf_ = d_ >> 18, sj_ = (d_ >> 5) & 0x1FFF, nv_ = d_ & 31;           \
        if (kf_ != curKf) {                                                    \
            curKf = kf_;                                                       \
            const __bf16* wk_ = wtb + kf_ * 4096;                              \
            _Pragma("unroll")                                                  \
            for (int n = 0; n < 4; ++n) {                                      \
                bfrag[n][0] = *reinterpret_cast<const bf16x8*>(                \
                    wk_ + (n * 16 + lrow) * 64 + lkB);                         \
                bfrag[n][1] = *reinterpret_cast<const bf16x8*>(                \
                    wk_ + (n * 16 + lrow) * 64 + 32 + lkB);                    \
            }                                                                  \
        }                                                                      \
        int ors_[4];                                                           \
        _Pragma("unroll")                                                      \
        for (int r = 0; r < 4; ++r) {                                          \
            int q_ = rg4 + r;                                                  \
            int idx_ = sj_ + (q_ < nv_ ? q_ : 0);                              \
            int e_ = (idx_ < stged) ? eLds[idx_] : entries[blockStart + idx_]; \
            ors_[r] = e_ & 127;                                                \
        }                                                                      \
        f32x4 acc_[4];                                                         \
        _Pragma("unroll")                                                      \
        for (int n = 0; n < 4; ++n) {                                          \
            acc_[n] = __builtin_amdgcn_mfma_f32_16x16x32_bf16(                 \
                A0, bfrag[n][0], (f32x4){0.f, 0.f, 0.f, 0.f}, 0, 0, 0);        \
            acc_[n] = __builtin_amdgcn_mfma_f32_16x16x32_bf16(                 \
                A1, bfrag[n][1], acc_[n], 0, 0, 0);                            \
        }                                                                      \
        _Pragma("unroll")                                                      \
        for (int r = 0; r < 4; ++r) {                                          \
            if (rg4 + r < nv_) {                                               \
                _Pragma("unroll")                                              \
                for (int n = 0; n < 4; ++n)                                    \
                    atomicAdd(&outT[ors_[r]][n * 16 + lrow], acc_[n][r]);      \
            }                                                                  \
        }                                                                      \
    } while (0)

    if (g0 < g1) {
        bf16x8 a00, a01, a10, a11, a20, a21, a30, a31;
        bf16x8 bfrag[4][2];
        int curKf = -1;
        if (g0 + 0 < g1) LOADG(g0 + 0, a00, a01);
        if (g0 + 1 < g1) LOADG(g0 + 1, a10, a11);
        if (g0 + 2 < g1) LOADG(g0 + 2, a20, a21);
        if (g0 + 3 < g1) LOADG(g0 + 3, a30, a31);
        for (int base = g0; base < g1; base += 4) {
            COMPG(base + 0, a00, a01);
            if (base + 4 < g1) LOADG(base + 4, a00, a01);
            if (base + 1 < g1) {
                COMPG(base + 1, a10, a11);
                if (base + 5 < g1) LOADG(base + 5, a10, a11);
            }
            if (base + 2 < g1) {
                COMPG(base + 2, a20, a21);
                if (base + 6 < g1) LOADG(base + 6, a20, a21);
            }
            if (base + 3 < g1) {
                COMPG(base + 3, a30, a31);
                if (base + 7 < g1) LOADG(base + 7, a30, a31);
            }
        }
    }
#undef LOADG
#undef COMPG

    __syncthreads();
    const int rowBase = b * RB;
    #pragma unroll
    for (int j = 0; j < 6; ++j) {
        int idx = j * 1024 + t * 4;
        int r = idx >> 6, c = idx & 63;
        int gr = rowBase + r;
        if (gr < N_ACTIVE) {
            f32x4 bv = *reinterpret_cast<const f32x4*>(&bias[c]);
            f32x4 v  = *reinterpret_cast<const f32x4*>(&outT[r][c]);
            v += bv;
            __builtin_nontemporal_store(v, reinterpret_cast<f32x4*>(&out[gr * 64 + c]));
        }
    }
}

extern "C" void kernel_launch(void* const* d_in, const int* in_sizes, int n_in,
                              void* d_out, int out_size, void* d_ws, size_t ws_size,
                              hipStream_t stream) {
    const float* feat    = (const float*)d_in[0];
    const float* weight  = (const float*)d_in[1];
    const float* bias    = (const float*)d_in[2];
    const int*   in_idx  = (const int*)d_in[3];
    const int*   out_idx = (const int*)d_in[4];
    float* out = (float*)d_out;

    char* wsb = (char*)d_ws;
    __bf16* featb = (__bf16*)wsb;                               // 25,600,000 B
    __bf16* wtb   = (__bf16*)(wsb + 25600000);                  //    221,184 B
    int* cnt      = (int*)(wsb + 25600000 + 221184);
    int* cursor   = cnt + NBUCK;
    int* off      = cursor + NBUCK;                             // NBUCK+1
    int* bsum     = off + NBUCK + 1;                            // NSB
    int* entries  = bsum + NSB;                                 // TOTP

    zero_ints<<<dim3((NBUCK + 255) / 256), dim3(256), 0, stream>>>(cnt, NBUCK);
    prep_fused<<<dim3(CF_BLOCKS + CW_BLOCKS + HI_BLOCKS), dim3(256), 0, stream>>>(
        feat, featb, weight, wtb, out_idx, cnt);
    scan1<<<dim3(NSB), dim3(256), 0, stream>>>(cnt, off, bsum);
    scan2<<<dim3(1), dim3(256), 0, stream>>>(bsum);
    scan3<<<dim3(NSB), dim3(256), 0, stream>>>(off, bsum, cursor);
    scatter_pack<<<dim3((TOTP + 255) / 256), dim3(256), 0, stream>>>(in_idx, out_idx, cursor, entries);
    conv_mfma<<<dim3(NB), dim3(256), 0, stream>>>(featb, wtb, bias, off, entries, out);
}

// Round 7
// 1274.999 us; speedup vs baseline: 1.0201x; 1.0201x over previous
//
#include <hip/hip_runtime.h>

#define N_ACTIVE 200000
#define N_IN 64
#define N_OUT 64
#define K_FILT 27
#define R_PAIRS 100000
#define TOTP (K_FILT * R_PAIRS)          // 2,700,000
#define RB 96                            // output rows per block
#define NB ((N_ACTIVE + RB - 1) / RB)    // 2084
#define NBUCK (NB * K_FILT)              // 56,268
#define NSB ((NBUCK + 255) / 256)        // 220
#define MAXG 256                         // group descriptors per block (max ~110)

#define CF_BLOCKS (N_ACTIVE * N_IN / 8 / 256)    // 6250 convert_feat blocks
#define CW_BLOCKS K_FILT                          // 27 convert_wt blocks
#define HI_BLOCKS ((TOTP + 255) / 256)            // 10547 hist blocks

typedef __bf16 bf16x8 __attribute__((ext_vector_type(8)));
typedef float f32x4 __attribute__((ext_vector_type(4)));

__global__ __launch_bounds__(256) void zero_ints(int* __restrict__ p, int n) {
    int i = blockIdx.x * 256 + threadIdx.x;
    if (i < n) p[i] = 0;
}

// ---------------------------------------------------------------------------
// fused prep: convert_feat | convert_wt | hist
// ---------------------------------------------------------------------------
__global__ __launch_bounds__(256) void prep_fused(
    const float* __restrict__ feat, __bf16* __restrict__ featb,
    const float* __restrict__ wsrc, __bf16* __restrict__ wt,
    const int* __restrict__ out_idx, int* __restrict__ cnt)
{
    int bb = blockIdx.x, t = threadIdx.x;
    if (bb < CF_BLOCKS) {
        int i = bb * 256 + t;
        const f32x4* src = reinterpret_cast<const f32x4*>(feat) + 2 * (size_t)i;
        f32x4 v0 = __builtin_nontemporal_load(src);
        f32x4 v1 = __builtin_nontemporal_load(src + 1);
        bf16x8 o;
        o[0] = (__bf16)v0[0]; o[1] = (__bf16)v0[1]; o[2] = (__bf16)v0[2]; o[3] = (__bf16)v0[3];
        o[4] = (__bf16)v1[0]; o[5] = (__bf16)v1[1]; o[6] = (__bf16)v1[2]; o[7] = (__bf16)v1[3];
        reinterpret_cast<bf16x8*>(featb)[i] = o;
    } else if (bb < CF_BLOCKS + CW_BLOCKS) {
        int kf = bb - CF_BLOCKS;
        const float* wk = wsrc + kf * 4096;
        __bf16* wo = wt + kf * 4096;
        int o = t >> 2, i0 = (t & 3) * 16;
        bf16x8 a, b;
        #pragma unroll
        for (int j = 0; j < 8; ++j) a[j] = (__bf16)wk[(i0 + j) * 64 + o];
        #pragma unroll
        for (int j = 0; j < 8; ++j) b[j] = (__bf16)wk[(i0 + 8 + j) * 64 + o];
        *reinterpret_cast<bf16x8*>(wo + o * 64 + i0) = a;
        *reinterpret_cast<bf16x8*>(wo + o * 64 + i0 + 8) = b;
    } else {
        int p = (bb - CF_BLOCKS - CW_BLOCKS) * 256 + t;
        if (p < TOTP) {
            unsigned k = (unsigned)p / (unsigned)R_PAIRS;
            int b = (out_idx[p] / RB) * K_FILT + (int)k;
            atomicAdd(&cnt[b], 1);
        }
    }
}

// ---- hierarchical exclusive scan over NBUCK counters ----
__global__ __launch_bounds__(256) void scan1(const int* __restrict__ cnt,
                                             int* __restrict__ off,
                                             int* __restrict__ bsum) {
    __shared__ int s[256];
    int t = threadIdx.x, i = blockIdx.x * 256 + t;
    int v = (i < NBUCK) ? cnt[i] : 0;
    s[t] = v;
    __syncthreads();
    #pragma unroll
    for (int d = 1; d < 256; d <<= 1) {
        int x = (t >= d) ? s[t - d] : 0;
        __syncthreads();
        s[t] += x;
        __syncthreads();
    }
    if (i < NBUCK) off[i] = s[t] - v;
    if (t == 255) bsum[blockIdx.x] = s[255];
}

__global__ __launch_bounds__(256) void scan2(int* __restrict__ bsum) {
    __shared__ int s[256];
    int t = threadIdx.x;
    int v = (t < NSB) ? bsum[t] : 0;
    s[t] = v;
    __syncthreads();
    #pragma unroll
    for (int d = 1; d < 256; d <<= 1) {
        int x = (t >= d) ? s[t - d] : 0;
        __syncthreads();
        s[t] += x;
        __syncthreads();
    }
    if (t < NSB) bsum[t] = s[t] - v;
}

__global__ __launch_bounds__(256) void scan3(int* __restrict__ off,
                                             const int* __restrict__ bsum,
                                             int* __restrict__ cursor) {
    int t = threadIdx.x, i = blockIdx.x * 256 + t;
    if (i < NBUCK) {
        int v = off[i] + bsum[blockIdx.x];
        off[i] = v;
        cursor[i] = v;
    }
    if (i == 0) off[NBUCK] = TOTP;
}

// ---------------------------------------------------------------------------
// scatter pair -> bucket list; entry packed as (in_row << 7) | out_local
// ---------------------------------------------------------------------------
__global__ __launch_bounds__(256) void scatter_pack(const int* __restrict__ in_idx,
                                                    const int* __restrict__ out_idx,
                                                    int* __restrict__ cursor,
                                                    int* __restrict__ entries) {
    int p = blockIdx.x * 256 + threadIdx.x;
    if (p >= TOTP) return;
    unsigned k = (unsigned)p / (unsigned)R_PAIRS;
    int orow = out_idx[p];
    int iv = __builtin_nontemporal_load(&in_idx[p]);
    int rg = orow / RB;
    int bkt = rg * K_FILT + (int)k;
    int pos = atomicAdd(&cursor[bkt], 1);
    entries[pos] = (iv << 7) | (orow - rg * RB);
}

// ---------------------------------------------------------------------------
// conv: block owns 96 out rows. Flat group descriptors (kf<<18|startJ<<5|nv)
// built in parallel. Each wave: contiguous descriptor range, TRUE 4-deep
// register pipeline {entry,a0,a1} with __launch_bounds__(256,4) so the
// compiler has 128 VGPRs. ors recovered from the entry reg via __shfl.
// MFMA layouts as r3 (verified).
// ---------------------------------------------------------------------------
__global__ __launch_bounds__(256, 4) void conv_mfma(
    const __bf16* __restrict__ featb,   // [N_ACTIVE][64] bf16
    const __bf16* __restrict__ wtb,     // [K][o][i] bf16 transposed
    const float* __restrict__ bias,
    const int* __restrict__ off,        // [NBUCK+1]
    const int* __restrict__ entries,    // [TOTP] packed
    float* __restrict__ out)            // [N_ACTIVE][64] fp32
{
    __shared__ float outT[RB][68];      // 26,112 B
    __shared__ int   sOff[K_FILT + 1];
    __shared__ int   descLds[MAXG];     //  1,024 B
    __shared__ int   gc[32];
    __shared__ int   gCount;

    const int b = blockIdx.x;
    const int t = threadIdx.x;
    const int w = t >> 6;
    const int lane = t & 63;
    const int lrow = lane & 15;
    const int lkB  = (lane >> 4) * 8;
    const int rg4  = (lane >> 4) * 4;
    const int bK = b * K_FILT;

    if (t < K_FILT + 1) sOff[t] = off[bK + t];

    {   // zero out tile
        f32x4 z = {0.f, 0.f, 0.f, 0.f};
        f32x4* o4 = reinterpret_cast<f32x4*>(&outT[0][0]);
        #pragma unroll
        for (int j = 0; j < 7; ++j) {
            int i = j * 256 + t;
            if (i < RB * 68 / 4) o4[i] = z;
        }
    }
    __syncthreads();

    // ---- parallel descriptor build ----
    if (t < K_FILT) {
        int c = sOff[t + 1] - sOff[t];
        gc[t] = (c + 15) >> 4;
    }
    __syncthreads();
    if (t == 0) {
        int s = 0;
        #pragma unroll
        for (int kf = 0; kf < K_FILT; ++kf) { int g = gc[kf]; gc[kf] = s; s += g; }
        gCount = s;
    }
    __syncthreads();
    if (t < K_FILT) {
        int base = sOff[t] - sOff[0];
        int c = sOff[t + 1] - sOff[t];
        int s = gc[t];
        for (int j = 0, g = 0; j < c; j += 16, ++g) {
            int nv = c - j; if (nv > 16) nv = 16;
            descLds[s + g] = (t << 18) | ((base + j) << 5) | nv;
        }
    }
    __syncthreads();

    const int blockStart = sOff[0];
    const int nG = gCount;
    const int per = (nG + 3) >> 2;
    const int g0 = w * per;
    const int g1 = (g0 + per < nG) ? g0 + per : nG;

#define LOADG(g, E, A0, A1) do {                                               \
        int d_ = descLds[g];                                                   \
        int sj_ = (d_ >> 5) & 0x1FFF, nv_ = d_ & 31;                           \
        E = entries[blockStart + sj_ + (lrow < nv_ ? lrow : 0)];               \
        const __bf16* ap_ = featb + (size_t)(E >> 7) * 64 + lkB;               \
        A0 = *reinterpret_cast<const bf16x8*>(ap_);                            \
        A1 = *reinterpret_cast<const bf16x8*>(ap_ + 32);                       \
    } while (0)

#define COMPG(g, E, A0, A1) do {                                               \
        int d_ = descLds[g];                                                   \
        int kf_ = d_ >> 18, nv_ = d_ & 31;                                     \
        if (kf_ != curKf) {                                                    \
            curKf = kf_;                                                       \
            const __bf16* wk_ = wtb + kf_ * 4096;                              \
            _Pragma("unroll")                                                  \
            for (int n = 0; n < 4; ++n) {                                      \
                bfrag[n][0] = *reinterpret_cast<const bf16x8*>(                \
                    wk_ + (n * 16 + lrow) * 64 + lkB);                         \
                bfrag[n][1] = *reinterpret_cast<const bf16x8*>(                \
                    wk_ + (n * 16 + lrow) * 64 + 32 + lkB);                    \
            }                                                                  \
        }                                                                      \
        f32x4 acc_[4];                                                         \
        _Pragma("unroll")                                                      \
        for (int n = 0; n < 4; ++n) {                                          \
            acc_[n] = __builtin_amdgcn_mfma_f32_16x16x32_bf16(                 \
                A0, bfrag[n][0], (f32x4){0.f, 0.f, 0.f, 0.f}, 0, 0, 0);        \
            acc_[n] = __builtin_amdgcn_mfma_f32_16x16x32_bf16(                 \
                A1, bfrag[n][1], acc_[n], 0, 0, 0);                            \
        }                                                                      \
        _Pragma("unroll")                                                      \
        for (int r = 0; r < 4; ++r) {                                          \
            int ors_ = __shfl(E, (lane & 48) | (rg4 + r)) & 127;               \
            if (rg4 + r < nv_) {                                               \
                _Pragma("unroll")                                              \
                for (int n = 0; n < 4; ++n)                                    \
                    atomicAdd(&outT[ors_][n * 16 + lrow], acc_[n][r]);         \
            }                                                                  \
        }                                                                      \
    } while (0)

    if (g0 < g1) {
        int e0, e1, e2, e3;
        bf16x8 a00, a01, a10, a11, a20, a21, a30, a31;
        bf16x8 bfrag[4][2];
        int curKf = -1;
        if (g0 + 0 < g1) LOADG(g0 + 0, e0, a00, a01);
        if (g0 + 1 < g1) LOADG(g0 + 1, e1, a10, a11);
        if (g0 + 2 < g1) LOADG(g0 + 2, e2, a20, a21);
        if (g0 + 3 < g1) LOADG(g0 + 3, e3, a30, a31);
        for (int base = g0; base < g1; base += 4) {
            COMPG(base + 0, e0, a00, a01);
            if (base + 4 < g1) LOADG(base + 4, e0, a00, a01);
            if (base + 1 < g1) {
                COMPG(base + 1, e1, a10, a11);
                if (base + 5 < g1) LOADG(base + 5, e1, a10, a11);
            }
            if (base + 2 < g1) {
                COMPG(base + 2, e2, a20, a21);
                if (base + 6 < g1) LOADG(base + 6, e2, a20, a21);
            }
            if (base + 3 < g1) {
                COMPG(base + 3, e3, a30, a31);
                if (base + 7 < g1) LOADG(base + 7, e3, a30, a31);
            }
        }
    }
#undef LOADG
#undef COMPG

    __syncthreads();
    const int rowBase = b * RB;
    #pragma unroll
    for (int j = 0; j < 6; ++j) {
        int idx = j * 1024 + t * 4;
        int r = idx >> 6, c = idx & 63;
        int gr = rowBase + r;
        if (gr < N_ACTIVE) {
            f32x4 bv = *reinterpret_cast<const f32x4*>(&bias[c]);
            f32x4 v  = *reinterpret_cast<const f32x4*>(&outT[r][c]);
            v += bv;
            __builtin_nontemporal_store(v, reinterpret_cast<f32x4*>(&out[gr * 64 + c]));
        }
    }
}

extern "C" void kernel_launch(void* const* d_in, const int* in_sizes, int n_in,
                              void* d_out, int out_size, void* d_ws, size_t ws_size,
                              hipStream_t stream) {
    const float* feat    = (const float*)d_in[0];
    const float* weight  = (const float*)d_in[1];
    const float* bias    = (const float*)d_in[2];
    const int*   in_idx  = (const int*)d_in[3];
    const int*   out_idx = (const int*)d_in[4];
    float* out = (float*)d_out;

    char* wsb = (char*)d_ws;
    __bf16* featb = (__bf16*)wsb;                               // 25,600,000 B
    __bf16* wtb   = (__bf16*)(wsb + 25600000);                  //    221,184 B
    int* cnt      = (int*)(wsb + 25600000 + 221184);
    int* cursor   = cnt + NBUCK;
    int* off      = cursor + NBUCK;                             // NBUCK+1
    int* bsum     = off + NBUCK + 1;                            // NSB
    int* entries  = bsum + NSB;                                 // TOTP

    zero_ints<<<dim3((NBUCK + 255) / 256), dim3(256), 0, stream>>>(cnt, NBUCK);
    prep_fused<<<dim3(CF_BLOCKS + CW_BLOCKS + HI_BLOCKS), dim3(256), 0, stream>>>(
        feat, featb, weight, wtb, out_idx, cnt);
    scan1<<<dim3(NSB), dim3(256), 0, stream>>>(cnt, off, bsum);
    scan2<<<dim3(1), dim3(256), 0, stream>>>(bsum);
    scan3<<<dim3(NSB), dim3(256), 0, stream>>>(off, bsum, cursor);
    scatter_pack<<<dim3((TOTP + 255) / 256), dim3(256), 0, stream>>>(in_idx, out_idx, cursor, entries);
    conv_mfma<<<dim3(NB), dim3(256), 0, stream>>>(featb, wtb, bias, off, entries, out);
}